// Round 7
// baseline (4072.217 us; speedup 1.0000x reference)
//
#include <hip/hip_runtime.h>
#include <hip/hip_bf16.h>

typedef short short8 __attribute__((ext_vector_type(8)));
typedef float f32x4 __attribute__((ext_vector_type(4)));
typedef unsigned long long u64;
typedef unsigned u32;

constexpr int S = 256, B = 64, IN = 512, H = 1024;
constexpr int M = S * B;        // 16384
constexpr int NG = 4 * H;       // 4096

// ---------------- prep: fp32 -> bf16 ----------------
__global__ void f2b(const float* __restrict__ s, __hip_bfloat16* __restrict__ d, int n4) {
  int i = blockIdx.x * blockDim.x + threadIdx.x;
  if (i >= n4) return;
  float4 v = reinterpret_cast<const float4*>(s)[i];
  __hip_bfloat16 o[4] = {__float2bfloat16(v.x), __float2bfloat16(v.y),
                         __float2bfloat16(v.z), __float2bfloat16(v.w)};
  *reinterpret_cast<uint2*>(d + 4 * (size_t)i) = *reinterpret_cast<uint2*>(o);
}

__global__ void bias_k(const float* bx0, const float* bx1, const float* bx2, const float* bx3,
                       const float* bh0, const float* bh1, const float* bh2, const float* bh3,
                       float* bias) {
  int i = blockIdx.x * blockDim.x + threadIdx.x;
  if (i >= NG) return;
  int g = i >> 10, j = i & 1023;
  const float* bx = g == 0 ? bx0 : g == 1 ? bx1 : g == 2 ? bx2 : bx3;
  const float* bh = g == 0 ? bh0 : g == 1 ? bh1 : g == 2 ? bh2 : bh3;
  bias[i] = bx[j] + bh[j];
}

// ---------------- gx = x @ Wx^T + bias : m97-structure, output [m][j][gate] ----------------
__global__ __launch_bounds__(256) void gx_gemm(const __hip_bfloat16* __restrict__ xb,
                                               const __hip_bfloat16* __restrict__ wxb,
                                               const float* __restrict__ bias,
                                               __hip_bfloat16* __restrict__ gx) {
  __shared__ __align__(16) ushort As[4][128][8];   // 8 KB
  __shared__ __align__(16) ushort Bs[4][128][8];   // 8 KB
  const int tid = threadIdx.x;
  const int l = tid & 63, w = tid >> 6;
  const int m0 = blockIdx.y * 128, n0 = blockIdx.x * 128;
  const int wm = (w >> 1) * 64, wn = (w & 1) * 64;
  const int cr = l & 15, kg = l >> 4;
  f32x4 acc[4][4] = {};

  ushort* Af = &As[0][0][0];
  ushort* Bfl = &Bs[0][0][0];

  for (int k0 = 0; k0 < IN; k0 += 32) {
    __syncthreads();
#pragma unroll
    for (int n = 0; n < 2; ++n) {
      int cA = w * 2 + n;            // chunk 0..7 (1 KB each)
      int f = cA * 64 + l;           // flat 16B-unit index: seg=f>>7, row=f&127
      const __hip_bfloat16* ga = xb + (size_t)(m0 + (f & 127)) * IN + k0 + (f >> 7) * 8;
      const __hip_bfloat16* gb = wxb + (size_t)(n0 + (f & 127)) * IN + k0 + (f >> 7) * 8;
      __builtin_amdgcn_global_load_lds((const u32*)ga, (u32*)(Af + cA * 512), 16, 0, 0);
      __builtin_amdgcn_global_load_lds((const u32*)gb, (u32*)(Bfl + cA * 512), 16, 0, 0);
    }
    __syncthreads();
    short8 a[4], b[4];
#pragma unroll
    for (int mi = 0; mi < 4; ++mi)
      a[mi] = *reinterpret_cast<const short8*>(&As[kg][wm + mi * 16 + cr][0]);
#pragma unroll
    for (int ni = 0; ni < 4; ++ni)
      b[ni] = *reinterpret_cast<const short8*>(&Bs[kg][wn + ni * 16 + cr][0]);
#pragma unroll
    for (int mi = 0; mi < 4; ++mi)
#pragma unroll
      for (int ni = 0; ni < 4; ++ni)
        acc[mi][ni] = __builtin_amdgcn_mfma_f32_16x16x32_bf16(a[mi], b[ni], acc[mi][ni], 0, 0, 0);
  }

#pragma unroll
  for (int ni = 0; ni < 4; ++ni) {
    int n = n0 + wn + ni * 16 + cr;
    float bv = bias[n];
    int g = n >> 10, j = n & 1023;
#pragma unroll
    for (int mi = 0; mi < 4; ++mi) {
#pragma unroll
      for (int r = 0; r < 4; ++r) {
        int m = m0 + wm + mi * 16 + kg * 4 + r;
        gx[((size_t)m * H + j) * 4 + g] = __float2bfloat16(acc[mi][ni][r] + bv);
      }
    }
  }
}

__device__ __forceinline__ u64 ldq(const u64* p) {
  return __hip_atomic_load(p, __ATOMIC_RELAXED, __HIP_MEMORY_SCOPE_AGENT);
}
__device__ __forceinline__ void stw(u32* p, u32 v) {
  __hip_atomic_store(p, v, __ATOMIC_RELAXED, __HIP_MEMORY_SCOPE_AGENT);
}
__device__ __forceinline__ float sigm(float x) {
  return __builtin_amdgcn_rcpf(1.f + __expf(-x));
}
__device__ __forceinline__ float tanhfast(float x) {
  return 2.f * __builtin_amdgcn_rcpf(1.f + __expf(-2.f * x)) - 1.f;
}

// ---------------- persistent recurrence: 1 wave/block, tagged-dataflow h ----------------
// 256 blocks x 64 threads. Block (bg,jg) owns output tile: batches b0..b0+15,
// hidden j0..j0+15, all 4 gates, full K=1024. Wh slice (128 KB) LDS-resident ->
// 1 block/CU. h word = (bf16 << 16) | step_tag; consumers' validating loads ARE
// the sync (single L3 leg). No barriers, fences, flags, or cross-wave reduction.
__global__ __launch_bounds__(64, 1) void lstm_rec(const __hip_bfloat16* __restrict__ whb,
                                                  const __hip_bfloat16* __restrict__ gx,
                                                  u32* __restrict__ hx,
                                                  float* __restrict__ out) {
  __shared__ __align__(16) ushort Bf[4][32][64][8];   // 128 KB: Wh slice, B-frag order
  const int l = threadIdx.x;
  const int jg = blockIdx.x & 63, bg = blockIdx.x >> 6;
  const int j0 = jg * 16, b0 = bg * 16;
  const int cr = l & 15, kg = l >> 4;

  // stage Wh slice into LDS, pre-swizzled to MFMA B-fragment order (once)
  for (int idx = l; idx < 4 * 32 * 64; idx += 64) {
    int g = idx >> 11, kb = (idx >> 6) & 31, ll = idx & 63;
    const __hip_bfloat16* src =
        whb + ((size_t)(g * H + j0 + (ll & 15))) * H + kb * 32 + (ll >> 4) * 8;
    *reinterpret_cast<uint4*>(&Bf[g][kb][ll][0]) = *reinterpret_cast<const uint4*>(src);
  }
  __syncthreads();

  const int jc = j0 + cr;              // this lane's output column
  float c[4] = {0.f, 0.f, 0.f, 0.f};   // cell state, rows (l>>4)*4 + r

  for (int t = 0; t < S; ++t) {
    const u64* hp = reinterpret_cast<const u64*>(hx + (size_t)(t & 1) * (B * H)) +
                    (size_t)(b0 + cr) * (H / 2) + kg * 4;
    u32* hdst = hx + (size_t)((t + 1) & 1) * (B * H);

    // gx prefetch: 4 gates packed per (row, j) -> one u64 per output row
    u64 gq[4];
#pragma unroll
    for (int r = 0; r < 4; ++r) {
      int m = t * B + b0 + (kg << 2) + r;
      gq[r] = *reinterpret_cast<const u64*>(gx + ((size_t)m * H + jc) * 4);
    }

    // issue all 128 tagged u64 loads (A rows = b0+cr, this lane's k-slices)
    u64 q[128];
    if (t > 0) {
#pragma unroll
      for (int r = 0; r < 128; ++r) q[r] = ldq(hp + (r >> 2) * 16 + (r & 3));
      // parallel-round validation: stale words re-issued concurrently
      const u64 tagpat = (u64)(u32)t | ((u64)(u32)t << 32);
      bool allok;
      do {
        allok = true;
#pragma unroll
        for (int r = 0; r < 128; ++r) {
          if (((q[r] ^ tagpat) & 0x0000ffff0000ffffull) != 0ull) {
            allok = false;
            q[r] = ldq(hp + (r >> 2) * 16 + (r & 3));
          }
        }
      } while (!allok);
    } else {
#pragma unroll
      for (int r = 0; r < 128; ++r) q[r] = 0;
    }

    // 32 k-chunks: unpack frag + 4 ds_read_b128 + 4 MFMA each
    f32x4 acc[4] = {};
#pragma unroll
    for (int kb = 0; kb < 32; ++kb) {
      u32 w0 = (u32)q[kb * 4 + 0], w1 = (u32)(q[kb * 4 + 0] >> 32);
      u32 w2 = (u32)q[kb * 4 + 1], w3 = (u32)(q[kb * 4 + 1] >> 32);
      u32 w4 = (u32)q[kb * 4 + 2], w5 = (u32)(q[kb * 4 + 2] >> 32);
      u32 w6 = (u32)q[kb * 4 + 3], w7 = (u32)(q[kb * 4 + 3] >> 32);
      union { u32 u[4]; short8 s; } ua;
      ua.u[0] = (w0 >> 16) | (w1 & 0xffff0000u);
      ua.u[1] = (w2 >> 16) | (w3 & 0xffff0000u);
      ua.u[2] = (w4 >> 16) | (w5 & 0xffff0000u);
      ua.u[3] = (w6 >> 16) | (w7 & 0xffff0000u);
#pragma unroll
      for (int g = 0; g < 4; ++g) {
        short8 bv = *reinterpret_cast<const short8*>(&Bf[g][kb][l][0]);
        acc[g] = __builtin_amdgcn_mfma_f32_16x16x32_bf16(ua.s, bv, acc[g], 0, 0, 0);
      }
    }

    // gates: lane owns col jc, rows b0 + (l>>4)*4 + r
#pragma unroll
    for (int r = 0; r < 4; ++r) {
      int br = b0 + (kg << 2) + r;
      float gf = acc[0][r] + __uint_as_float((u32)(gq[r] & 0xffffu) << 16);
      float gi = acc[1][r] + __uint_as_float((u32)((gq[r] >> 16) & 0xffffu) << 16);
      float go = acc[2][r] + __uint_as_float((u32)((gq[r] >> 32) & 0xffffu) << 16);
      float gc = acc[3][r] + __uint_as_float((u32)((gq[r] >> 48) & 0xffffu) << 16);
      float f = sigm(gf);
      float i_ = sigm(gi);
      float o = sigm(go);
      float cn = f * c[r] + i_ * tanhfast(gc);
      float hn = o * tanhfast(cn);
      c[r] = cn;

      out[((size_t)(t * B) + br) * H + jc] = hn;
      if (t == S - 1) {
        out[(size_t)S * B * H + (size_t)br * H + jc] = hn;
        out[(size_t)S * B * H + (size_t)B * H + (size_t)br * H + jc] = cn;
      }
      // publish tagged h word (single sc1 store; the consumers' loads are the sync)
      if (t < S - 1) {
        u32 word = ((u32)__bfloat16_as_ushort(__float2bfloat16(hn)) << 16) | (u32)(t + 1);
        stw(hdst + (size_t)br * H + jc, word);
      }
    }
  }
}

extern "C" void kernel_launch(void* const* d_in, const int* in_sizes, int n_in,
                              void* d_out, int out_size, void* d_ws, size_t ws_size,
                              hipStream_t stream) {
  const float* x = (const float*)d_in[0];
  const float* Wx[4] = {(const float*)d_in[1], (const float*)d_in[3],
                        (const float*)d_in[5], (const float*)d_in[7]};
  const float* bx[4] = {(const float*)d_in[2], (const float*)d_in[4],
                        (const float*)d_in[6], (const float*)d_in[8]};
  const float* Wh[4] = {(const float*)d_in[9], (const float*)d_in[11],
                        (const float*)d_in[13], (const float*)d_in[15]};
  const float* bh[4] = {(const float*)d_in[10], (const float*)d_in[12],
                        (const float*)d_in[14], (const float*)d_in[16]};

  char* ws = (char*)d_ws;
  size_t o_hx = 0;                                    // 2*B*H u32 = 512 KB
  size_t o_bias = o_hx + (size_t)2 * B * H * 4;
  size_t o_x = o_bias + (size_t)NG * 4;
  size_t o_wx = o_x + (size_t)M * IN * 2;
  size_t o_wh = o_wx + (size_t)NG * IN * 2;
  size_t o_gx = o_wh + (size_t)NG * H * 2;

  u32* hxp = (u32*)(ws + o_hx);
  float* biasp = (float*)(ws + o_bias);
  __hip_bfloat16* xb = (__hip_bfloat16*)(ws + o_x);
  __hip_bfloat16* wxb = (__hip_bfloat16*)(ws + o_wx);
  __hip_bfloat16* whb = (__hip_bfloat16*)(ws + o_wh);
  __hip_bfloat16* gxp = (__hip_bfloat16*)(ws + o_gx);

  // zero hx each launch: clears stale tags from previous graph replay
  hipMemsetAsync(ws, 0, o_bias, stream);

  f2b<<<(M * IN / 4) / 256, 256, 0, stream>>>(x, xb, M * IN / 4);
  for (int g = 0; g < 4; ++g)
    f2b<<<(H * IN / 4) / 256, 256, 0, stream>>>(Wx[g], wxb + (size_t)g * H * IN, H * IN / 4);
  for (int g = 0; g < 4; ++g)
    f2b<<<(H * H / 4) / 256, 256, 0, stream>>>(Wh[g], whb + (size_t)g * H * H, H * H / 4);
  bias_k<<<NG / 256, 256, 0, stream>>>(bx[0], bx[1], bx[2], bx[3],
                                       bh[0], bh[1], bh[2], bh[3], biasp);

  dim3 gg(NG / 128, M / 128);
  gx_gemm<<<gg, 256, 0, stream>>>(xb, wxb, biasp, gxp);

  lstm_rec<<<256, 64, 0, stream>>>(whb, gxp, hxp, (float*)d_out);
}

// Round 8
// 2094.233 us; speedup vs baseline: 1.9445x; 1.9445x over previous
//
#include <hip/hip_runtime.h>
#include <hip/hip_bf16.h>

typedef short short8 __attribute__((ext_vector_type(8)));
typedef float f32x4 __attribute__((ext_vector_type(4)));
typedef unsigned long long u64;
typedef unsigned u32;

constexpr int S = 256, B = 64, IN = 512, H = 1024;
constexpr int M = S * B;        // 16384
constexpr int NG = 4 * H;       // 4096

// ---------------- prep: fp32 -> bf16 ----------------
__global__ void f2b(const float* __restrict__ s, __hip_bfloat16* __restrict__ d, int n4) {
  int i = blockIdx.x * blockDim.x + threadIdx.x;
  if (i >= n4) return;
  float4 v = reinterpret_cast<const float4*>(s)[i];
  __hip_bfloat16 o[4] = {__float2bfloat16(v.x), __float2bfloat16(v.y),
                         __float2bfloat16(v.z), __float2bfloat16(v.w)};
  *reinterpret_cast<uint2*>(d + 4 * (size_t)i) = *reinterpret_cast<uint2*>(o);
}

__global__ void bias_k(const float* bx0, const float* bx1, const float* bx2, const float* bx3,
                       const float* bh0, const float* bh1, const float* bh2, const float* bh3,
                       float* bias) {
  int i = blockIdx.x * blockDim.x + threadIdx.x;
  if (i >= NG) return;
  int g = i >> 10, j = i & 1023;
  const float* bx = g == 0 ? bx0 : g == 1 ? bx1 : g == 2 ? bx2 : bx3;
  const float* bh = g == 0 ? bh0 : g == 1 ? bh1 : g == 2 ? bh2 : bh3;
  bias[i] = bx[j] + bh[j];
}

// ---------------- gx = x @ Wx^T + bias : m97-structure, output [m][j][gate] ----------------
__global__ __launch_bounds__(256) void gx_gemm(const __hip_bfloat16* __restrict__ xb,
                                               const __hip_bfloat16* __restrict__ wxb,
                                               const float* __restrict__ bias,
                                               __hip_bfloat16* __restrict__ gx) {
  __shared__ __align__(16) ushort As[4][128][8];   // 8 KB
  __shared__ __align__(16) ushort Bs[4][128][8];   // 8 KB
  const int tid = threadIdx.x;
  const int l = tid & 63, w = tid >> 6;
  const int m0 = blockIdx.y * 128, n0 = blockIdx.x * 128;
  const int wm = (w >> 1) * 64, wn = (w & 1) * 64;
  const int cr = l & 15, kg = l >> 4;
  f32x4 acc[4][4] = {};

  ushort* Af = &As[0][0][0];
  ushort* Bfl = &Bs[0][0][0];

  for (int k0 = 0; k0 < IN; k0 += 32) {
    __syncthreads();
#pragma unroll
    for (int n = 0; n < 2; ++n) {
      int cA = w * 2 + n;            // chunk 0..7 (1 KB each)
      int f = cA * 64 + l;           // flat 16B-unit index: seg=f>>7, row=f&127
      const __hip_bfloat16* ga = xb + (size_t)(m0 + (f & 127)) * IN + k0 + (f >> 7) * 8;
      const __hip_bfloat16* gb = wxb + (size_t)(n0 + (f & 127)) * IN + k0 + (f >> 7) * 8;
      __builtin_amdgcn_global_load_lds((const u32*)ga, (u32*)(Af + cA * 512), 16, 0, 0);
      __builtin_amdgcn_global_load_lds((const u32*)gb, (u32*)(Bfl + cA * 512), 16, 0, 0);
    }
    __syncthreads();
    short8 a[4], b[4];
#pragma unroll
    for (int mi = 0; mi < 4; ++mi)
      a[mi] = *reinterpret_cast<const short8*>(&As[kg][wm + mi * 16 + cr][0]);
#pragma unroll
    for (int ni = 0; ni < 4; ++ni)
      b[ni] = *reinterpret_cast<const short8*>(&Bs[kg][wn + ni * 16 + cr][0]);
#pragma unroll
    for (int mi = 0; mi < 4; ++mi)
#pragma unroll
      for (int ni = 0; ni < 4; ++ni)
        acc[mi][ni] = __builtin_amdgcn_mfma_f32_16x16x32_bf16(a[mi], b[ni], acc[mi][ni], 0, 0, 0);
  }

#pragma unroll
  for (int ni = 0; ni < 4; ++ni) {
    int n = n0 + wn + ni * 16 + cr;
    float bv = bias[n];
    int g = n >> 10, j = n & 1023;
#pragma unroll
    for (int mi = 0; mi < 4; ++mi) {
#pragma unroll
      for (int r = 0; r < 4; ++r) {
        int m = m0 + wm + mi * 16 + kg * 4 + r;
        gx[((size_t)m * H + j) * 4 + g] = __float2bfloat16(acc[mi][ni][r] + bv);
      }
    }
  }
}

__device__ __forceinline__ u64 ldq(const u64* p) {
  return __hip_atomic_load(p, __ATOMIC_RELAXED, __HIP_MEMORY_SCOPE_AGENT);
}
__device__ __forceinline__ u32 ldw(const u32* p) {
  return __hip_atomic_load(p, __ATOMIC_RELAXED, __HIP_MEMORY_SCOPE_AGENT);
}
__device__ __forceinline__ void stw(u32* p, u32 v) {
  __hip_atomic_store(p, v, __ATOMIC_RELAXED, __HIP_MEMORY_SCOPE_AGENT);
}
__device__ __forceinline__ float sigm(float x) {
  return __builtin_amdgcn_rcpf(1.f + __expf(-x));
}
__device__ __forceinline__ float tanhfast(float x) {
  return 2.f * __builtin_amdgcn_rcpf(1.f + __expf(-2.f * x)) - 1.f;
}
// block barrier that only drains LDS (no vmcnt(0) -> no L3 store-ack RTT)
__device__ __forceinline__ void bar_lds() {
  asm volatile("s_waitcnt lgkmcnt(0)" ::: "memory");
  __builtin_amdgcn_sched_barrier(0);
  __builtin_amdgcn_s_barrier();
  __builtin_amdgcn_sched_barrier(0);
}

// ---------------- persistent recurrence: tagged-dataflow, sentinel-gated ----------------
// 256 blocks (bg*64+jg? -> blockIdx=bg<<6|jg) x 4 waves. Wave w: K in [w*256,+256),
// all 4 gates; cross-wave K-reduction via gt LDS. Wh slice (128 KB) LDS-resident ->
// 1 block/CU. h word = (bf16<<16)|step_tag. Consumers spin on 64 SENTINEL words
// (4 per producer), then bulk-validate 32 u64/thread with parallel retry rounds.
// No vmcnt drains, no flags, no fences in the loop.
__global__ __launch_bounds__(256, 1) void lstm_rec(const __hip_bfloat16* __restrict__ whb,
                                                   const __hip_bfloat16* __restrict__ gx,
                                                   u32* __restrict__ hx,
                                                   float* __restrict__ out) {
  __shared__ __align__(16) ushort Bf[4][32][64][8];   // 128 KB: Wh slice, B-frag order
  __shared__ __align__(16) float gt[4][4][16][20];    // 20 KB
  const int tid = threadIdx.x;
  const int l = tid & 63, w = tid >> 6;
  const int jg = blockIdx.x & 63, bg = blockIdx.x >> 6;
  const int j0 = jg * 16, b0 = bg * 16;

  // stage Wh slice into LDS, pre-swizzled to MFMA B-fragment order (once)
  for (int idx = tid; idx < 4 * 32 * 64; idx += 256) {
    int g = idx >> 11, kb = (idx >> 6) & 31, ll = idx & 63;
    const __hip_bfloat16* src =
        whb + ((size_t)(g * H + j0 + (ll & 15))) * H + kb * 32 + (ll >> 4) * 8;
    *reinterpret_cast<uint4*>(&Bf[g][kb][ll][0]) = *reinterpret_cast<const uint4*>(src);
  }
  __syncthreads();

  const int cr = l & 15, kg = l >> 4;
  const int bi = tid >> 4, j = tid & 15;
  float c = 0.f;

  for (int t = 0; t < S; ++t) {
    const u32* hsrc = hx + (size_t)(t & 1) * (B * H);
    u32* hdst = hx + (size_t)((t + 1) & 1) * (B * H);

    // gx prefetch: 4 gates packed -> one u64 per thread (plain cached load)
    const u64 gq = *reinterpret_cast<const u64*>(
        gx + ((size_t)(t * B + b0 + bi) * H + j0 + j) * 4);

    union { u64 q[2]; short8 s; } ua[8];
    if (t > 0) {
      // issue all 32 bulk loads early (independent)
      const u64* hp =
          reinterpret_cast<const u64*>(hsrc + (size_t)(b0 + cr) * H + w * 256 + kg * 8);
      u64 q[32];
#pragma unroll
      for (int kk = 0; kk < 8; ++kk) {
#pragma unroll
        for (int x = 0; x < 4; ++x) q[kk * 4 + x] = ldq(hp + kk * 16 + x);
      }

      // sentinel spin: lane l covers producer jg'=w*16+(l&15), wave-group row (l>>4)*4+3
      const u32* sent =
          hsrc + (size_t)(b0 + (l >> 4) * 4 + 3) * H + (w * 16 + (l & 15)) * 16 + 15;
      bool ok;
      do {
        u32 sv = ldw(sent);
        ok = __all((sv & 0xffffu) == (u32)t);
      } while (!ok);

      // bulk validation: re-issue all stale words concurrently (parallel rounds)
      const u64 tagpat = (u64)(u32)t | ((u64)(u32)t << 32);
      bool allok;
      do {
        allok = true;
#pragma unroll
        for (int r = 0; r < 32; ++r) {
          if (((q[r] ^ tagpat) & 0x0000ffff0000ffffull) != 0ull) {
            allok = false;
            q[r] = ldq(hp + (r >> 2) * 16 + (r & 3));
          }
        }
      } while (!allok);

#pragma unroll
      for (int kk = 0; kk < 8; ++kk) {
        u32 w0 = (u32)q[kk * 4 + 0], w1 = (u32)(q[kk * 4 + 0] >> 32);
        u32 w2 = (u32)q[kk * 4 + 1], w3 = (u32)(q[kk * 4 + 1] >> 32);
        u32 w4 = (u32)q[kk * 4 + 2], w5 = (u32)(q[kk * 4 + 2] >> 32);
        u32 w6 = (u32)q[kk * 4 + 3], w7 = (u32)(q[kk * 4 + 3] >> 32);
        ua[kk].q[0] = (u64)((w0 >> 16) | (w1 & 0xffff0000u)) |
                      ((u64)((w2 >> 16) | (w3 & 0xffff0000u)) << 32);
        ua[kk].q[1] = (u64)((w4 >> 16) | (w5 & 0xffff0000u)) |
                      ((u64)((w6 >> 16) | (w7 & 0xffff0000u)) << 32);
      }
    } else {
#pragma unroll
      for (int kk = 0; kk < 8; ++kk) { ua[kk].q[0] = 0; ua[kk].q[1] = 0; }
    }

    // MFMA partials over this wave's K range (B-frags from LDS)
    f32x4 acc[4] = {};
#pragma unroll
    for (int kk = 0; kk < 8; ++kk) {
#pragma unroll
      for (int g = 0; g < 4; ++g) {
        short8 bv = *reinterpret_cast<const short8*>(&Bf[g][w * 8 + kk][l][0]);
        acc[g] = __builtin_amdgcn_mfma_f32_16x16x32_bf16(ua[kk].s, bv, acc[g], 0, 0, 0);
      }
    }
#pragma unroll
    for (int g = 0; g < 4; ++g)
      *reinterpret_cast<f32x4*>(&gt[w][g][cr][kg * 4]) = acc[g];
    bar_lds();   // gt writes visible; no vmcnt drain

    // cross-wave K reduction + gates (thread owns (batch=bi, hidden=j))
    float sf = 0.f, si = 0.f, so = 0.f, sc = 0.f;
#pragma unroll
    for (int wv = 0; wv < 4; ++wv) {
      sf += gt[wv][0][j][bi];
      si += gt[wv][1][j][bi];
      so += gt[wv][2][j][bi];
      sc += gt[wv][3][j][bi];
    }
    float gf = sf + __uint_as_float((u32)(gq & 0xffffu) << 16);
    float gi = si + __uint_as_float((u32)((gq >> 16) & 0xffffu) << 16);
    float go = so + __uint_as_float((u32)((gq >> 32) & 0xffffu) << 16);
    float gc = sc + __uint_as_float((u32)((gq >> 48) & 0xffffu) << 16);
    float f = sigm(gf);
    float i_ = sigm(gi);
    float o = sigm(go);
    float cn = f * c + i_ * tanhfast(gc);
    float hn = o * tanhfast(cn);
    c = cn;

    // publish FIRST (critical path), then background out stores
    if (t < S - 1) {
      u32 word = ((u32)__bfloat16_as_ushort(__float2bfloat16(hn)) << 16) | (u32)(t + 1);
      stw(hdst + (size_t)(b0 + bi) * H + j0 + j, word);
    }
    out[((size_t)(t * B + b0 + bi)) * H + j0 + j] = hn;
    if (t == S - 1) {
      out[(size_t)S * B * H + (size_t)(b0 + bi) * H + j0 + j] = hn;
      out[(size_t)S * B * H + (size_t)B * H + (size_t)(b0 + bi) * H + j0 + j] = cn;
    }

    bar_lds();   // gt reads done before next iteration's writes
  }
}

extern "C" void kernel_launch(void* const* d_in, const int* in_sizes, int n_in,
                              void* d_out, int out_size, void* d_ws, size_t ws_size,
                              hipStream_t stream) {
  const float* x = (const float*)d_in[0];
  const float* Wx[4] = {(const float*)d_in[1], (const float*)d_in[3],
                        (const float*)d_in[5], (const float*)d_in[7]};
  const float* bx[4] = {(const float*)d_in[2], (const float*)d_in[4],
                        (const float*)d_in[6], (const float*)d_in[8]};
  const float* Wh[4] = {(const float*)d_in[9], (const float*)d_in[11],
                        (const float*)d_in[13], (const float*)d_in[15]};
  const float* bh[4] = {(const float*)d_in[10], (const float*)d_in[12],
                        (const float*)d_in[14], (const float*)d_in[16]};

  char* ws = (char*)d_ws;
  size_t o_hx = 0;                                    // 2*B*H u32 = 512 KB
  size_t o_bias = o_hx + (size_t)2 * B * H * 4;
  size_t o_x = o_bias + (size_t)NG * 4;
  size_t o_wx = o_x + (size_t)M * IN * 2;
  size_t o_wh = o_wx + (size_t)NG * IN * 2;
  size_t o_gx = o_wh + (size_t)NG * H * 2;

  u32* hxp = (u32*)(ws + o_hx);
  float* biasp = (float*)(ws + o_bias);
  __hip_bfloat16* xb = (__hip_bfloat16*)(ws + o_x);
  __hip_bfloat16* wxb = (__hip_bfloat16*)(ws + o_wx);
  __hip_bfloat16* whb = (__hip_bfloat16*)(ws + o_wh);
  __hip_bfloat16* gxp = (__hip_bfloat16*)(ws + o_gx);

  // zero hx each launch: tag 0 == step 0 (h_0 = 0), clears stale tags from replay
  hipMemsetAsync(ws, 0, o_bias, stream);

  f2b<<<(M * IN / 4) / 256, 256, 0, stream>>>(x, xb, M * IN / 4);
  for (int g = 0; g < 4; ++g)
    f2b<<<(H * IN / 4) / 256, 256, 0, stream>>>(Wx[g], wxb + (size_t)g * H * IN, H * IN / 4);
  for (int g = 0; g < 4; ++g)
    f2b<<<(H * H / 4) / 256, 256, 0, stream>>>(Wh[g], whb + (size_t)g * H * H, H * H / 4);
  bias_k<<<NG / 256, 256, 0, stream>>>(bx[0], bx[1], bx[2], bx[3],
                                       bh[0], bh[1], bh[2], bh[3], biasp);

  dim3 gg(NG / 128, M / 128);
  gx_gemm<<<gg, 256, 0, stream>>>(xb, wxb, biasp, gxp);

  lstm_rec<<<256, 256, 0, stream>>>(whb, gxp, hxp, (float*)d_out);
}

// Round 9
// 1772.055 us; speedup vs baseline: 2.2980x; 1.1818x over previous
//
#include <hip/hip_runtime.h>
#include <hip/hip_bf16.h>

typedef short short8 __attribute__((ext_vector_type(8)));
typedef float f32x4 __attribute__((ext_vector_type(4)));
typedef unsigned long long u64;
typedef unsigned u32;

constexpr int S = 256, B = 64, IN = 512, H = 1024;
constexpr int M = S * B;        // 16384
constexpr int NG = 4 * H;       // 4096

// ---------------- prep: fp32 -> bf16 ----------------
__global__ void f2b(const float* __restrict__ s, __hip_bfloat16* __restrict__ d, int n4) {
  int i = blockIdx.x * blockDim.x + threadIdx.x;
  if (i >= n4) return;
  float4 v = reinterpret_cast<const float4*>(s)[i];
  __hip_bfloat16 o[4] = {__float2bfloat16(v.x), __float2bfloat16(v.y),
                         __float2bfloat16(v.z), __float2bfloat16(v.w)};
  *reinterpret_cast<uint2*>(d + 4 * (size_t)i) = *reinterpret_cast<uint2*>(o);
}

__global__ void bias_k(const float* bx0, const float* bx1, const float* bx2, const float* bx3,
                       const float* bh0, const float* bh1, const float* bh2, const float* bh3,
                       float* bias) {
  int i = blockIdx.x * blockDim.x + threadIdx.x;
  if (i >= NG) return;
  int g = i >> 10, j = i & 1023;
  const float* bx = g == 0 ? bx0 : g == 1 ? bx1 : g == 2 ? bx2 : bx3;
  const float* bh = g == 0 ? bh0 : g == 1 ? bh1 : g == 2 ? bh2 : bh3;
  bias[i] = bx[j] + bh[j];
}

// ---------------- gx = x @ Wx^T + bias : m97-structure, output [m][j][gate] ----------------
__global__ __launch_bounds__(256) void gx_gemm(const __hip_bfloat16* __restrict__ xb,
                                               const __hip_bfloat16* __restrict__ wxb,
                                               const float* __restrict__ bias,
                                               __hip_bfloat16* __restrict__ gx) {
  __shared__ __align__(16) ushort As[4][128][8];   // 8 KB
  __shared__ __align__(16) ushort Bs[4][128][8];   // 8 KB
  const int tid = threadIdx.x;
  const int l = tid & 63, w = tid >> 6;
  const int m0 = blockIdx.y * 128, n0 = blockIdx.x * 128;
  const int wm = (w >> 1) * 64, wn = (w & 1) * 64;
  const int cr = l & 15, kg = l >> 4;
  f32x4 acc[4][4] = {};

  ushort* Af = &As[0][0][0];
  ushort* Bfl = &Bs[0][0][0];

  for (int k0 = 0; k0 < IN; k0 += 32) {
    __syncthreads();
#pragma unroll
    for (int n = 0; n < 2; ++n) {
      int cA = w * 2 + n;            // chunk 0..7 (1 KB each)
      int f = cA * 64 + l;           // flat 16B-unit index: seg=f>>7, row=f&127
      const __hip_bfloat16* ga = xb + (size_t)(m0 + (f & 127)) * IN + k0 + (f >> 7) * 8;
      const __hip_bfloat16* gb = wxb + (size_t)(n0 + (f & 127)) * IN + k0 + (f >> 7) * 8;
      __builtin_amdgcn_global_load_lds((const u32*)ga, (u32*)(Af + cA * 512), 16, 0, 0);
      __builtin_amdgcn_global_load_lds((const u32*)gb, (u32*)(Bfl + cA * 512), 16, 0, 0);
    }
    __syncthreads();
    short8 a[4], b[4];
#pragma unroll
    for (int mi = 0; mi < 4; ++mi)
      a[mi] = *reinterpret_cast<const short8*>(&As[kg][wm + mi * 16 + cr][0]);
#pragma unroll
    for (int ni = 0; ni < 4; ++ni)
      b[ni] = *reinterpret_cast<const short8*>(&Bs[kg][wn + ni * 16 + cr][0]);
#pragma unroll
    for (int mi = 0; mi < 4; ++mi)
#pragma unroll
      for (int ni = 0; ni < 4; ++ni)
        acc[mi][ni] = __builtin_amdgcn_mfma_f32_16x16x32_bf16(a[mi], b[ni], acc[mi][ni], 0, 0, 0);
  }

#pragma unroll
  for (int ni = 0; ni < 4; ++ni) {
    int n = n0 + wn + ni * 16 + cr;
    float bv = bias[n];
    int g = n >> 10, j = n & 1023;
#pragma unroll
    for (int mi = 0; mi < 4; ++mi) {
#pragma unroll
      for (int r = 0; r < 4; ++r) {
        int m = m0 + wm + mi * 16 + kg * 4 + r;
        gx[((size_t)m * H + j) * 4 + g] = __float2bfloat16(acc[mi][ni][r] + bv);
      }
    }
  }
}

__device__ __forceinline__ u64 ldq(const u64* p) {
  return __hip_atomic_load(p, __ATOMIC_RELAXED, __HIP_MEMORY_SCOPE_AGENT);
}
__device__ __forceinline__ u32 ldw(const u32* p) {
  return __hip_atomic_load(p, __ATOMIC_RELAXED, __HIP_MEMORY_SCOPE_AGENT);
}
__device__ __forceinline__ void stw(u32* p, u32 v) {
  __hip_atomic_store(p, v, __ATOMIC_RELAXED, __HIP_MEMORY_SCOPE_AGENT);
}
__device__ __forceinline__ float sigm(float x) {
  return __builtin_amdgcn_rcpf(1.f + __expf(-x));
}
__device__ __forceinline__ float tanhfast(float x) {
  return 2.f * __builtin_amdgcn_rcpf(1.f + __expf(-2.f * x)) - 1.f;
}
// block barrier that only drains LDS (no vmcnt(0) -> no store-ack RTT)
__device__ __forceinline__ void bar_lds() {
  asm volatile("s_waitcnt lgkmcnt(0)" ::: "memory");
  __builtin_amdgcn_sched_barrier(0);
  __builtin_amdgcn_s_barrier();
  __builtin_amdgcn_sched_barrier(0);
}

// ---------------- persistent recurrence: flag-gated + tag-validated h ----------------
// 256 blocks (bg<<6|jg) x 4 waves. Wave w: K in [w*256,+256), all 4 gates,
// cross-wave reduction via gt LDS. Wh (128 KB) LDS-resident -> 1 block/CU.
// Producer: tagged h stores (bf16<<16|step), then PER-WAVE flag store with NO
// vmcnt drain (program order only). Consumer: polls 64 per-wave flags (1 word/
// lane, monotone hot slots), then bulk-loads h once; tags catch reordered
// stragglers via parallel retry rounds (rare).
__global__ __launch_bounds__(256, 1) void lstm_rec(const __hip_bfloat16* __restrict__ whb,
                                                   const __hip_bfloat16* __restrict__ gx,
                                                   u32* __restrict__ hx,
                                                   u32* __restrict__ flags,
                                                   float* __restrict__ out) {
  __shared__ __align__(16) ushort Bf[4][32][64][8];   // 128 KB: Wh slice, B-frag order
  __shared__ __align__(16) float gt[4][4][16][20];    // 20 KB
  const int tid = threadIdx.x;
  const int l = tid & 63, w = tid >> 6;
  const int jg = blockIdx.x & 63, bg = blockIdx.x >> 6;
  const int j0 = jg * 16, b0 = bg * 16;

  // stage Wh slice into LDS, pre-swizzled to MFMA B-fragment order (once)
  for (int idx = tid; idx < 4 * 32 * 64; idx += 256) {
    int g = idx >> 11, kb = (idx >> 6) & 31, ll = idx & 63;
    const __hip_bfloat16* src =
        whb + ((size_t)(g * H + j0 + (ll & 15))) * H + kb * 32 + (ll >> 4) * 8;
    *reinterpret_cast<uint4*>(&Bf[g][kb][ll][0]) = *reinterpret_cast<const uint4*>(src);
  }
  __syncthreads();

  const int cr = l & 15, kg = l >> 4;
  const int bi = tid >> 4, j = tid & 15;
  // consumer poll target: producer block (bg, jg'=w*16+(l&15)), wave pw=(l>>4)
  const u32* myfl =
      flags + ((size_t)((bg * 64 + w * 16 + (l & 15)) * 4 + (l >> 4))) * 16;
  // producer flag slot for this block's wave w
  u32* pubfl = flags + ((size_t)((bg * 64 + jg) * 4 + w)) * 16;
  float c = 0.f;

  for (int t = 0; t < S; ++t) {
    const u32* hsrc = hx + (size_t)(t & 1) * (B * H);
    u32* hdst = hx + (size_t)((t + 1) & 1) * (B * H);

    // gx prefetch: 4 gates packed -> one u64 per thread (plain cached load)
    const u64 gq = *reinterpret_cast<const u64*>(
        gx + ((size_t)(t * B + b0 + bi) * H + j0 + j) * 4);

    union { u64 q[2]; short8 s; } ua[8];
    if (t > 0) {
      // flag wait: 1 word per lane, monotone counters (hot lines)
      while (!__all(ldw(myfl) >= (u32)t)) __builtin_amdgcn_s_sleep(1);
      asm volatile("" ::: "memory");

      // bulk load ONCE after detect (mostly fresh), tag-validate with
      // parallel retry rounds for reordered stragglers
      const u64* hp = reinterpret_cast<const u64*>(hsrc + (size_t)(b0 + cr) * H) +
                      w * 128 + kg * 4;
      u64 q[32];
#pragma unroll
      for (int kk = 0; kk < 8; ++kk) {
#pragma unroll
        for (int x = 0; x < 4; ++x) q[kk * 4 + x] = ldq(hp + kk * 16 + x);
      }
      const u64 tagpat = (u64)(u32)t | ((u64)(u32)t << 32);
      bool allok;
      do {
        allok = true;
#pragma unroll
        for (int r = 0; r < 32; ++r) {
          if (((q[r] ^ tagpat) & 0x0000ffff0000ffffull) != 0ull) {
            allok = false;
            q[r] = ldq(hp + (r >> 2) * 16 + (r & 3));
          }
        }
      } while (!allok);

#pragma unroll
      for (int kk = 0; kk < 8; ++kk) {
        u32 w0 = (u32)q[kk * 4 + 0], w1 = (u32)(q[kk * 4 + 0] >> 32);
        u32 w2 = (u32)q[kk * 4 + 1], w3 = (u32)(q[kk * 4 + 1] >> 32);
        u32 w4 = (u32)q[kk * 4 + 2], w5 = (u32)(q[kk * 4 + 2] >> 32);
        u32 w6 = (u32)q[kk * 4 + 3], w7 = (u32)(q[kk * 4 + 3] >> 32);
        ua[kk].q[0] = (u64)((w0 >> 16) | (w1 & 0xffff0000u)) |
                      ((u64)((w2 >> 16) | (w3 & 0xffff0000u)) << 32);
        ua[kk].q[1] = (u64)((w4 >> 16) | (w5 & 0xffff0000u)) |
                      ((u64)((w6 >> 16) | (w7 & 0xffff0000u)) << 32);
      }
    } else {
#pragma unroll
      for (int kk = 0; kk < 8; ++kk) { ua[kk].q[0] = 0; ua[kk].q[1] = 0; }
    }

    // MFMA partials over this wave's K range (B-frags from LDS)
    f32x4 acc[4] = {};
#pragma unroll
    for (int kk = 0; kk < 8; ++kk) {
#pragma unroll
      for (int g = 0; g < 4; ++g) {
        short8 bv = *reinterpret_cast<const short8*>(&Bf[g][w * 8 + kk][l][0]);
        acc[g] = __builtin_amdgcn_mfma_f32_16x16x32_bf16(ua[kk].s, bv, acc[g], 0, 0, 0);
      }
    }
#pragma unroll
    for (int g = 0; g < 4; ++g)
      *reinterpret_cast<f32x4*>(&gt[w][g][cr][kg * 4]) = acc[g];
    bar_lds();   // gt writes visible (lgkmcnt only)

    // cross-wave K reduction + gates (thread owns (batch=bi, hidden=j))
    float sf = 0.f, si = 0.f, so = 0.f, sc = 0.f;
#pragma unroll
    for (int wv = 0; wv < 4; ++wv) {
      sf += gt[wv][0][j][bi];
      si += gt[wv][1][j][bi];
      so += gt[wv][2][j][bi];
      sc += gt[wv][3][j][bi];
    }
    float gf = sf + __uint_as_float((u32)(gq & 0xffffu) << 16);
    float gi = si + __uint_as_float((u32)((gq >> 16) & 0xffffu) << 16);
    float go = so + __uint_as_float((u32)((gq >> 32) & 0xffffu) << 16);
    float gc = sc + __uint_as_float((u32)((gq >> 48) & 0xffffu) << 16);
    float f = sigm(gf);
    float i_ = sigm(gi);
    float o = sigm(go);
    float cn = f * c + i_ * tanhfast(gc);
    float hn = o * tanhfast(cn);
    c = cn;

    // publish tagged h word, then per-wave flag immediately (NO drain);
    // background out stores afterwards (off the protocol path)
    if (t < S - 1) {
      u32 word = ((u32)__bfloat16_as_ushort(__float2bfloat16(hn)) << 16) | (u32)(t + 1);
      stw(hdst + (size_t)(b0 + bi) * H + j0 + j, word);
      if (l == 0) stw(pubfl, (u32)(t + 1));
    }
    out[((size_t)(t * B + b0 + bi)) * H + j0 + j] = hn;
    if (t == S - 1) {
      out[(size_t)S * B * H + (size_t)(b0 + bi) * H + j0 + j] = hn;
      out[(size_t)S * B * H + (size_t)B * H + (size_t)(b0 + bi) * H + j0 + j] = cn;
    }

    bar_lds();   // gt reads done before next iteration's writes
  }
}

extern "C" void kernel_launch(void* const* d_in, const int* in_sizes, int n_in,
                              void* d_out, int out_size, void* d_ws, size_t ws_size,
                              hipStream_t stream) {
  const float* x = (const float*)d_in[0];
  const float* Wx[4] = {(const float*)d_in[1], (const float*)d_in[3],
                        (const float*)d_in[5], (const float*)d_in[7]};
  const float* bx[4] = {(const float*)d_in[2], (const float*)d_in[4],
                        (const float*)d_in[6], (const float*)d_in[8]};
  const float* Wh[4] = {(const float*)d_in[9], (const float*)d_in[11],
                        (const float*)d_in[13], (const float*)d_in[15]};
  const float* bh[4] = {(const float*)d_in[10], (const float*)d_in[12],
                        (const float*)d_in[14], (const float*)d_in[16]};

  char* ws = (char*)d_ws;
  size_t o_flags = 0;                                 // 1024 slots x 64B = 64 KB
  size_t o_hx = 65536;
  size_t o_bias = o_hx + (size_t)2 * B * H * 4;       // hx ping-pong u32: 512 KB
  size_t o_x = o_bias + (size_t)NG * 4;
  size_t o_wx = o_x + (size_t)M * IN * 2;
  size_t o_wh = o_wx + (size_t)NG * IN * 2;
  size_t o_gx = o_wh + (size_t)NG * H * 2;

  u32* flagsp = (u32*)(ws + o_flags);
  u32* hxp = (u32*)(ws + o_hx);
  float* biasp = (float*)(ws + o_bias);
  __hip_bfloat16* xb = (__hip_bfloat16*)(ws + o_x);
  __hip_bfloat16* wxb = (__hip_bfloat16*)(ws + o_wx);
  __hip_bfloat16* whb = (__hip_bfloat16*)(ws + o_wh);
  __hip_bfloat16* gxp = (__hip_bfloat16*)(ws + o_gx);

  // zero flags + hx each launch (clears stale tags/counters from prior replay)
  hipMemsetAsync(ws, 0, o_bias, stream);

  f2b<<<(M * IN / 4) / 256, 256, 0, stream>>>(x, xb, M * IN / 4);
  for (int g = 0; g < 4; ++g)
    f2b<<<(H * IN / 4) / 256, 256, 0, stream>>>(Wx[g], wxb + (size_t)g * H * IN, H * IN / 4);
  for (int g = 0; g < 4; ++g)
    f2b<<<(H * H / 4) / 256, 256, 0, stream>>>(Wh[g], whb + (size_t)g * H * H, H * H / 4);
  bias_k<<<NG / 256, 256, 0, stream>>>(bx[0], bx[1], bx[2], bx[3],
                                       bh[0], bh[1], bh[2], bh[3], biasp);

  dim3 gg(NG / 128, M / 128);
  gx_gemm<<<gg, 256, 0, stream>>>(xb, wxb, biasp, gxp);

  lstm_rec<<<256, 256, 0, stream>>>(whb, gxp, hxp, flagsp, (float*)d_out);
}

// Round 10
// 1193.407 us; speedup vs baseline: 3.4123x; 1.4849x over previous
//
#include <hip/hip_runtime.h>
#include <hip/hip_bf16.h>

typedef short short8 __attribute__((ext_vector_type(8)));
typedef float f32x4 __attribute__((ext_vector_type(4)));
typedef unsigned long long u64;
typedef unsigned u32;

constexpr int S = 256, B = 64, IN = 512, H = 1024;
constexpr int M = S * B;        // 16384
constexpr int NG = 4 * H;       // 4096

// ---------------- prep ----------------
__global__ void f2b(const float* __restrict__ s, __hip_bfloat16* __restrict__ d, int n4) {
  int i = blockIdx.x * blockDim.x + threadIdx.x;
  if (i >= n4) return;
  float4 v = reinterpret_cast<const float4*>(s)[i];
  __hip_bfloat16 o[4] = {__float2bfloat16(v.x), __float2bfloat16(v.y),
                         __float2bfloat16(v.z), __float2bfloat16(v.w)};
  *reinterpret_cast<uint2*>(d + 4 * (size_t)i) = *reinterpret_cast<uint2*>(o);
}

// all 8 weight matrices in one launch: Wx 4x(H*IN) then Wh 4x(H*H), float4 units
__global__ void wconv(const float* w0, const float* w1, const float* w2, const float* w3,
                      const float* w4, const float* w5, const float* w6, const float* w7,
                      __hip_bfloat16* __restrict__ wxb, __hip_bfloat16* __restrict__ whb) {
  const int QX = H * IN / 4;     // 131072 float4 per Wx gate
  const int QH = H * H / 4;      // 262144 float4 per Wh gate
  int i = blockIdx.x * blockDim.x + threadIdx.x;
  const float* src;
  __hip_bfloat16* dst;
  int off;
  if (i < 4 * QX) {
    int g = i / QX; off = i - g * QX;
    src = g == 0 ? w0 : g == 1 ? w1 : g == 2 ? w2 : w3;
    dst = wxb + (size_t)g * H * IN;
  } else {
    int k = i - 4 * QX;
    if (k >= 4 * QH) return;
    int g = k / QH; off = k - g * QH;
    src = g == 0 ? w4 : g == 1 ? w5 : g == 2 ? w6 : w7;
    dst = whb + (size_t)g * H * H;
  }
  float4 v = reinterpret_cast<const float4*>(src)[off];
  __hip_bfloat16 o[4] = {__float2bfloat16(v.x), __float2bfloat16(v.y),
                         __float2bfloat16(v.z), __float2bfloat16(v.w)};
  *reinterpret_cast<uint2*>(dst + 4 * (size_t)off) = *reinterpret_cast<uint2*>(o);
}

__global__ void bias_k(const float* bx0, const float* bx1, const float* bx2, const float* bx3,
                       const float* bh0, const float* bh1, const float* bh2, const float* bh3,
                       float* bias) {
  int i = blockIdx.x * blockDim.x + threadIdx.x;
  if (i >= NG) return;
  int g = i >> 10, j = i & 1023;
  const float* bx = g == 0 ? bx0 : g == 1 ? bx1 : g == 2 ? bx2 : bx3;
  const float* bh = g == 0 ? bh0 : g == 1 ? bh1 : g == 2 ? bh2 : bh3;
  bias[i] = bx[j] + bh[j];
}

// ---------------- gx = x @ Wx^T + bias : m97-structure, output [m][j][gate] ----------------
__global__ __launch_bounds__(256) void gx_gemm(const __hip_bfloat16* __restrict__ xb,
                                               const __hip_bfloat16* __restrict__ wxb,
                                               const float* __restrict__ bias,
                                               __hip_bfloat16* __restrict__ gx) {
  __shared__ __align__(16) ushort As[4][128][8];   // 8 KB
  __shared__ __align__(16) ushort Bs[4][128][8];   // 8 KB
  const int tid = threadIdx.x;
  const int l = tid & 63, w = tid >> 6;
  const int m0 = blockIdx.y * 128, n0 = blockIdx.x * 128;
  const int wm = (w >> 1) * 64, wn = (w & 1) * 64;
  const int cr = l & 15, kg = l >> 4;
  f32x4 acc[4][4] = {};

  ushort* Af = &As[0][0][0];
  ushort* Bfl = &Bs[0][0][0];

  for (int k0 = 0; k0 < IN; k0 += 32) {
    __syncthreads();
#pragma unroll
    for (int n = 0; n < 2; ++n) {
      int cA = w * 2 + n;            // chunk 0..7 (1 KB each)
      int f = cA * 64 + l;           // flat 16B-unit index: seg=f>>7, row=f&127
      const __hip_bfloat16* ga = xb + (size_t)(m0 + (f & 127)) * IN + k0 + (f >> 7) * 8;
      const __hip_bfloat16* gb = wxb + (size_t)(n0 + (f & 127)) * IN + k0 + (f >> 7) * 8;
      __builtin_amdgcn_global_load_lds((const u32*)ga, (u32*)(Af + cA * 512), 16, 0, 0);
      __builtin_amdgcn_global_load_lds((const u32*)gb, (u32*)(Bfl + cA * 512), 16, 0, 0);
    }
    __syncthreads();
    short8 a[4], b[4];
#pragma unroll
    for (int mi = 0; mi < 4; ++mi)
      a[mi] = *reinterpret_cast<const short8*>(&As[kg][wm + mi * 16 + cr][0]);
#pragma unroll
    for (int ni = 0; ni < 4; ++ni)
      b[ni] = *reinterpret_cast<const short8*>(&Bs[kg][wn + ni * 16 + cr][0]);
#pragma unroll
    for (int mi = 0; mi < 4; ++mi)
#pragma unroll
      for (int ni = 0; ni < 4; ++ni)
        acc[mi][ni] = __builtin_amdgcn_mfma_f32_16x16x32_bf16(a[mi], b[ni], acc[mi][ni], 0, 0, 0);
  }

#pragma unroll
  for (int ni = 0; ni < 4; ++ni) {
    int n = n0 + wn + ni * 16 + cr;
    float bv = bias[n];
    int g = n >> 10, j = n & 1023;
#pragma unroll
    for (int mi = 0; mi < 4; ++mi) {
#pragma unroll
      for (int r = 0; r < 4; ++r) {
        int m = m0 + wm + mi * 16 + kg * 4 + r;
        gx[((size_t)m * H + j) * 4 + g] = __float2bfloat16(acc[mi][ni][r] + bv);
      }
    }
  }
}

__device__ __forceinline__ u64 ldq(const u64* p) {
  return __hip_atomic_load(p, __ATOMIC_RELAXED, __HIP_MEMORY_SCOPE_AGENT);
}
__device__ __forceinline__ u32 ldw(const u32* p) {
  return __hip_atomic_load(p, __ATOMIC_RELAXED, __HIP_MEMORY_SCOPE_AGENT);
}
__device__ __forceinline__ void stw(u32* p, u32 v) {
  __hip_atomic_store(p, v, __ATOMIC_RELAXED, __HIP_MEMORY_SCOPE_AGENT);
}
__device__ __forceinline__ void stq(u64* p, u64 v) {
  __hip_atomic_store(p, v, __ATOMIC_RELAXED, __HIP_MEMORY_SCOPE_AGENT);
}
__device__ __forceinline__ float sigm(float x) {
  return __builtin_amdgcn_rcpf(1.f + __expf(-x));
}
__device__ __forceinline__ float tanhfast(float x) {
  return 2.f * __builtin_amdgcn_rcpf(1.f + __expf(-2.f * x)) - 1.f;
}
// block barrier that only drains LDS (no vmcnt -> no store-ack RTT)
__device__ __forceinline__ void bar_lds() {
  asm volatile("s_waitcnt lgkmcnt(0)" ::: "memory");
  __builtin_amdgcn_sched_barrier(0);
  __builtin_amdgcn_s_barrier();
  __builtin_amdgcn_sched_barrier(0);
}

// ---------------- persistent recurrence: drain -> per-block flag -> load-once ----------------
// 256 blocks (bg<<6|jg) x 4 waves. Wave w: K in [w*256,+256), all 4 gates,
// cross-wave reduction via gt LDS. Wh (128 KB) LDS-resident -> 1 block/CU.
// Producer: packed bf16 h stores (sc1) -> vmcnt(0) drain (h only; out stores are
// issued AFTER the flag) -> s_barrier -> ONE monotone flag/block (hot slot).
// Consumer wave polls its 16 producer blocks' flags, then loads h exactly once.
__global__ __launch_bounds__(256, 1) void lstm_rec(const __hip_bfloat16* __restrict__ whb,
                                                   const __hip_bfloat16* __restrict__ gx,
                                                   __hip_bfloat16* __restrict__ hx,
                                                   u32* __restrict__ flags,
                                                   float* __restrict__ out) {
  __shared__ __align__(16) ushort Bf[4][32][64][8];   // 128 KB: Wh slice, B-frag order
  __shared__ __align__(16) float gt[4][4][16][20];    // 20 KB
  const int tid = threadIdx.x;
  const int l = tid & 63, w = tid >> 6;
  const int jg = blockIdx.x & 63, bg = blockIdx.x >> 6;
  const int j0 = jg * 16, b0 = bg * 16;

  // stage Wh slice into LDS, pre-swizzled to MFMA B-fragment order (once)
  for (int idx = tid; idx < 4 * 32 * 64; idx += 256) {
    int g = idx >> 11, kb = (idx >> 6) & 31, ll = idx & 63;
    const __hip_bfloat16* src =
        whb + ((size_t)(g * H + j0 + (ll & 15))) * H + kb * 32 + (ll >> 4) * 8;
    *reinterpret_cast<uint4*>(&Bf[g][kb][ll][0]) = *reinterpret_cast<const uint4*>(src);
  }
  __syncthreads();

  const int cr = l & 15, kg = l >> 4;
  const int bi = tid >> 4, j = tid & 15;
  // consumer: wave w polls producers jg' = w*16 + (l&15) of its own bg (hot slots)
  const u32* myfl = flags + (size_t)((bg << 6) + w * 16 + (l & 15)) * 16;
  u32* pubfl = flags + (size_t)((bg << 6) + jg) * 16;
  float c = 0.f;

  for (int t = 0; t < S; ++t) {
    const __hip_bfloat16* hsrc = hx + (size_t)(t & 1) * (B * H);
    __hip_bfloat16* hdst = hx + (size_t)((t + 1) & 1) * (B * H);

    // gx prefetch: 4 gates packed -> one u64 per thread (plain cached load)
    const u64 gq = *reinterpret_cast<const u64*>(
        gx + ((size_t)(t * B + b0 + bi) * H + j0 + j) * 4);

    union { u64 q[2]; short8 s; } ua[8];
    if (t > 0) {
      // flag wait: one word/lane over this wave's 16 producer blocks
      while (!__all(ldw(myfl) >= (u32)t)) ;
      asm volatile("" ::: "memory");

      // h bulk load ONCE (fresh by protocol; these ARE the A-fragments)
      const u64* hp =
          reinterpret_cast<const u64*>(hsrc + (size_t)(b0 + cr) * H + w * 256 + kg * 8);
#pragma unroll
      for (int kk = 0; kk < 8; ++kk) {
        ua[kk].q[0] = ldq(hp + kk * 8);
        ua[kk].q[1] = ldq(hp + kk * 8 + 1);
      }
    } else {
#pragma unroll
      for (int kk = 0; kk < 8; ++kk) { ua[kk].q[0] = 0; ua[kk].q[1] = 0; }
    }

    // MFMA partials over this wave's K range (B-frags from LDS)
    f32x4 acc[4] = {};
#pragma unroll
    for (int kk = 0; kk < 8; ++kk) {
#pragma unroll
      for (int g = 0; g < 4; ++g) {
        short8 bv = *reinterpret_cast<const short8*>(&Bf[g][w * 8 + kk][l][0]);
        acc[g] = __builtin_amdgcn_mfma_f32_16x16x32_bf16(ua[kk].s, bv, acc[g], 0, 0, 0);
      }
    }
#pragma unroll
    for (int g = 0; g < 4; ++g)
      *reinterpret_cast<f32x4*>(&gt[w][g][cr][kg * 4]) = acc[g];
    bar_lds();   // gt writes visible (lgkm only)

    // cross-wave K reduction + gates (thread owns (batch=bi, hidden=j))
    float sf = 0.f, si = 0.f, so = 0.f, sc = 0.f;
#pragma unroll
    for (int wv = 0; wv < 4; ++wv) {
      sf += gt[wv][0][j][bi];
      si += gt[wv][1][j][bi];
      so += gt[wv][2][j][bi];
      sc += gt[wv][3][j][bi];
    }
    float gf = sf + __uint_as_float((u32)(gq & 0xffffu) << 16);
    float gi = si + __uint_as_float((u32)((gq >> 16) & 0xffffu) << 16);
    float go = so + __uint_as_float((u32)((gq >> 32) & 0xffffu) << 16);
    float gc = sc + __uint_as_float((u32)((gq >> 48) & 0xffffu) << 16);
    float f = sigm(gf);
    float i_ = sigm(gi);
    float o = sigm(go);
    float cn = f * c + i_ * tanhfast(gc);
    float hn = o * tanhfast(cn);
    c = cn;

    // ---- publish path FIRST: pack bf16 h (2 shfl), store, drain h only, flag ----
    u32 hs16 = (u32)__bfloat16_as_ushort(__float2bfloat16(hn));
    u32 p1 = (hs16 & 0xffffu) | ((u32)__shfl_xor((int)hs16, 1) << 16);
    u32 p2 = (u32)__shfl_xor((int)p1, 2);
    if (t < S - 1) {
      if ((j & 3) == 0) {
        u64 pk = (u64)p1 | ((u64)p2 << 32);
        stq(reinterpret_cast<u64*>(hdst + (size_t)(b0 + bi) * H + j0 + j), pk);
      }
      // drain THIS wave's h stores (L3 ack), join waves, publish one flag.
      // This s_barrier also serves as the gt WAR barrier for the next step.
      asm volatile("s_waitcnt vmcnt(0)" ::: "memory");
      __builtin_amdgcn_sched_barrier(0);
      __builtin_amdgcn_s_barrier();
      __builtin_amdgcn_sched_barrier(0);
      if (tid == 0) stw(pubfl, (u32)(t + 1));
    }

    // ---- off-path stores (issued after the flag; acks overlap next step) ----
    out[((size_t)(t * B + b0 + bi)) * H + j0 + j] = hn;
    if (t == S - 1) {
      out[(size_t)S * B * H + (size_t)(b0 + bi) * H + j0 + j] = hn;
      out[(size_t)S * B * H + (size_t)B * H + (size_t)(b0 + bi) * H + j0 + j] = cn;
    }
  }
}

extern "C" void kernel_launch(void* const* d_in, const int* in_sizes, int n_in,
                              void* d_out, int out_size, void* d_ws, size_t ws_size,
                              hipStream_t stream) {
  const float* x = (const float*)d_in[0];
  const float* Wx[4] = {(const float*)d_in[1], (const float*)d_in[3],
                        (const float*)d_in[5], (const float*)d_in[7]};
  const float* bx[4] = {(const float*)d_in[2], (const float*)d_in[4],
                        (const float*)d_in[6], (const float*)d_in[8]};
  const float* Wh[4] = {(const float*)d_in[9], (const float*)d_in[11],
                        (const float*)d_in[13], (const float*)d_in[15]};
  const float* bh[4] = {(const float*)d_in[10], (const float*)d_in[12],
                        (const float*)d_in[14], (const float*)d_in[16]};

  char* ws = (char*)d_ws;
  size_t o_flags = 0;                                 // 256 slots x 64B = 16 KB
  size_t o_hx = 16384;
  size_t o_bias = o_hx + (size_t)2 * B * H * 2;       // hx ping-pong bf16: 256 KB
  size_t o_x = o_bias + (size_t)NG * 4;
  size_t o_wx = o_x + (size_t)M * IN * 2;
  size_t o_wh = o_wx + (size_t)NG * IN * 2;
  size_t o_gx = o_wh + (size_t)NG * H * 2;

  u32* flagsp = (u32*)(ws + o_flags);
  __hip_bfloat16* hxp = (__hip_bfloat16*)(ws + o_hx);
  float* biasp = (float*)(ws + o_bias);
  __hip_bfloat16* xb = (__hip_bfloat16*)(ws + o_x);
  __hip_bfloat16* wxb = (__hip_bfloat16*)(ws + o_wx);
  __hip_bfloat16* whb = (__hip_bfloat16*)(ws + o_wh);
  __hip_bfloat16* gxp = (__hip_bfloat16*)(ws + o_gx);

  // zero only the 16 KB flag array each launch (monotone counters)
  hipMemsetAsync(ws, 0, 16384, stream);

  f2b<<<(M * IN / 4) / 256, 256, 0, stream>>>(x, xb, M * IN / 4);
  {
    int total4 = 4 * (H * IN / 4) + 4 * (H * H / 4);   // 1.5M float4
    wconv<<<(total4 + 255) / 256, 256, 0, stream>>>(
        Wx[0], Wx[1], Wx[2], Wx[3], Wh[0], Wh[1], Wh[2], Wh[3], wxb, whb);
  }
  bias_k<<<NG / 256, 256, 0, stream>>>(bx[0], bx[1], bx[2], bx[3],
                                       bh[0], bh[1], bh[2], bh[3], biasp);

  dim3 gg(NG / 128, M / 128);
  gx_gemm<<<gg, 256, 0, stream>>>(xb, wxb, biasp, gxp);

  lstm_rec<<<256, 256, 0, stream>>>(whb, gxp, hxp, flagsp, (float*)d_out);
}